// Round 18
// baseline (2695.176 us; speedup 1.0000x reference)
//
#include <hip/hip_runtime.h>

#define B_ 4
#define T_ 1024
#define E_ 1024
#define H_ 16
#define HD_ 64
#define L_ 8
#define V_ 32000
#define FF_ 4096
#define M_ (B_*T_)

typedef unsigned short u16;
typedef __attribute__((ext_vector_type(8))) short bf16x8;   // 8 bf16 = 4 VGPR
typedef __attribute__((ext_vector_type(4))) float f32x4;
typedef __attribute__((ext_vector_type(16))) float f32x16;

#define AS1V(p) ((__attribute__((address_space(1))) void*)(p))
#define AS3V(p) ((__attribute__((address_space(3))) void*)(p))
#define XSW(row) (((row) & 7) << 4)
#define XSW32(row) ((((row) ^ ((row) >> 3)) & 7) << 4)

#define GBAR  asm volatile("s_barrier" ::: "memory")
#define WLG0  asm volatile("s_waitcnt lgkmcnt(0)" ::: "memory")
#define WVM4  asm volatile("s_waitcnt vmcnt(4)" ::: "memory")
#define WVM6  asm volatile("s_waitcnt vmcnt(6)" ::: "memory")
#define WVM0  asm volatile("s_waitcnt vmcnt(0)" ::: "memory")

__device__ __forceinline__ u16 f2bf(float f) {              // RNE f32->bf16
    unsigned int u = __float_as_uint(f);
    u += 0x7FFFu + ((u >> 16) & 1u);
    return (u16)(u >> 16);
}
__device__ __forceinline__ float bf2f(u16 v) {
    return __uint_as_float(((unsigned int)v) << 16);
}
__device__ __forceinline__ float ldf(const float* p, long i) { return p[i]; }
__device__ __forceinline__ float ldf(const u16*   p, long i) { return bf2f(p[i]); }

// bijective XCD swizzle (m204): nwg workgroups -> chunk per XCD
__device__ __forceinline__ int xcd_swz(int orig, int nwg) {
    int q8 = nwg >> 3, r8 = nwg & 7;
    int xcd = orig & 7, sub = orig >> 3;
    return (xcd < r8 ? xcd*(q8+1) : r8*(q8+1) + (xcd-r8)*q8) + sub;
}

// ---------------- batched tiled transpose:  dst[N][K](bf16) = src[K][N] ----------------
template<typename ST>
__global__ void k_transpose(const ST* __restrict__ src, u16* __restrict__ dst,
                            int K, int N, long srs, long drs,
                            int ZH, long szb, long szh, long dzb, long dzh)
{
    __shared__ float tile[32][33];
    int z = blockIdx.z; int zb = z / ZH, zh = z % ZH;
    const ST* s = src + (long)zb*szb + (long)zh*szh;
    u16* d = dst + (long)zb*dzb + (long)zh*dzh;
    int k0 = blockIdx.y * 32, n0 = blockIdx.x * 32;
    int tx = threadIdx.x, ty = threadIdx.y;
    for (int i = ty; i < 32; i += 8) {
        int k = k0 + i, n = n0 + tx;
        tile[i][tx] = (k < K && n < N) ? ldf(s, (long)k*srs + n) : 0.f;
    }
    __syncthreads();
    for (int i = ty; i < 32; i += 8) {
        int n = n0 + i, k = k0 + tx;
        if (n < N && k < K) d[(long)n*drs + k] = f2bf(tile[tx][i]);
    }
}

// ---------------- merged QKV weight pack: Wq/Wk/Wv [L,H,E,HD] -> WqkvT [L][3E][E] ------
__global__ void k_packqkv(const float* __restrict__ Wq, const float* __restrict__ Wk,
                          const float* __restrict__ Wv, u16* __restrict__ dst)
{
    __shared__ float tile[32][33];
    int z = blockIdx.z;                 // 0 .. 3*L*H-1
    int s = z / (L_*H_);
    int lh = z % (L_*H_);
    int l = lh / H_, hh = lh % H_;
    const float* W = (s == 0 ? Wq : (s == 1 ? Wk : Wv));
    const float* src = W + ((long)l*H_ + hh)*(long)E_*HD_;   // [E][HD]
    u16* d = dst + ((size_t)l*3*E_ + (size_t)s*E_ + (size_t)hh*HD_) * E_;
    int k0 = blockIdx.y * 32, n0 = blockIdx.x * 32;          // k over E, n over HD
    int tx = threadIdx.x, ty = threadIdx.y;
    for (int i = ty; i < 32; i += 8)
        tile[i][tx] = src[(long)(k0 + i)*HD_ + n0 + tx];
    __syncthreads();
    for (int i = ty; i < 32; i += 8)
        d[(long)(n0 + i)*E_ + k0 + tx] = f2bf(tile[tx][i]);
}

// ---------------- token+pos embedding -> h (f32) ----------------
__global__ void k_embed(const int* __restrict__ x, const float* __restrict__ tok,
                        const float* __restrict__ pos, float* __restrict__ h)
{
    long i = (long)blockIdx.x * 256 + threadIdx.x;
    int e4 = (int)(i & (E_/4 - 1));
    long bt = i >> 8;
    int t = (int)(bt & (T_ - 1));
    int id = x[bt];
    float4 a = *(const float4*)(tok + (long)id*E_ + e4*4);
    float4 p = *(const float4*)(pos + (long)t*E_ + e4*4);
    float4 o; o.x=a.x+p.x; o.y=a.y+p.y; o.z=a.z+p.z; o.w=a.w+p.w;
    *(float4*)(h + bt*E_ + e4*4) = o;
}

// ---------------- layernorm (row of E=1024, block=256) -> bf16 ----------------
__global__ void k_ln(const float* __restrict__ in, const float* __restrict__ g,
                     const float* __restrict__ b, u16* __restrict__ out)
{
    int row = blockIdx.x, tid = threadIdx.x;
    float4 v = *(const float4*)(in + (long)row*E_ + tid*4);
    float s = v.x + v.y + v.z + v.w;
    float ss = v.x*v.x + v.y*v.y + v.z*v.z + v.w*v.w;
    #pragma unroll
    for (int o = 32; o; o >>= 1) { s += __shfl_down(s, o); ss += __shfl_down(ss, o); }
    __shared__ float r0[4], r1[4];
    if ((tid & 63) == 0) { r0[tid >> 6] = s; r1[tid >> 6] = ss; }
    __syncthreads();
    s  = r0[0] + r0[1] + r0[2] + r0[3];
    ss = r1[0] + r1[1] + r1[2] + r1[3];
    float mean = s * (1.f/E_);
    float rstd = rsqrtf(ss * (1.f/E_) - mean*mean + 1e-5f);
    float4 gv = *(const float4*)(g + tid*4);
    float4 bv = *(const float4*)(b + tid*4);
    ushort4 pk;
    pk.x = f2bf((v.x - mean)*rstd*gv.x + bv.x);
    pk.y = f2bf((v.y - mean)*rstd*gv.y + bv.y);
    pk.z = f2bf((v.z - mean)*rstd*gv.z + bv.z);
    pk.w = f2bf((v.w - mean)*rstd*gv.w + bv.w);
    *(ushort4*)(out + (long)row*E_ + tid*4) = pk;
}

// ---------------- flash attention: Q-tile 128 x KV-tiles 128, online softmax ----------
// K double-buffered (prefetched 1 tile ahead); V staged at loop top, latency hidden
// under QK^T+softmax. LDS 80KB: Ks0@0, Ks1@16K, Vts@32K, Pw@48K(+w*8K) -> 2 blocks/CU.
__global__ __launch_bounds__(256, 2)
void k_flash(const u16* __restrict__ qkv, const u16* __restrict__ vt,
             u16* __restrict__ attno)
{
    __shared__ alignas(16) char lds[81920];
    const int wg = xcd_swz(blockIdx.x, gridDim.x);
    const int bh = wg >> 3, qt = 7 - (wg & 7);      // heavy q-tiles first
    const int b = bh >> 4, hh = bh & 15;

    const int tid = threadIdx.x, w = tid >> 6, lane = tid & 63;
    const int fr = lane & 15, sel = lane >> 4;
    const int xs = XSW(fr);

    const char* qb = (const char*)(qkv + (long)b*T_*3*E_ + (size_t)hh*HD_);
    const char* kb = (const char*)(qkv + (long)b*T_*3*E_ + E_ + (size_t)hh*HD_);
    const char* vb = (const char*)(vt + (size_t)bh*HD_*T_);
    const int q0 = qt << 7;

    bf16x8 qa[2][2];
    #pragma unroll
    for (int rf = 0; rf < 2; ++rf)
        #pragma unroll
        for (int t = 0; t < 2; ++t) {
            int row = q0 + w*32 + rf*16 + fr;
            qa[rf][t] = *(const bf16x8*)(qb + (long)row*(3*E_*2) + t*64 + sel*16);
        }

    f32x4 oacc[2][4];
    float mrow[2][4], lrow[2][4];
    #pragma unroll
    for (int rf = 0; rf < 2; ++rf) {
        #pragma unroll
        for (int cf = 0; cf < 4; ++cf) oacc[rf][cf] = (f32x4){0.f,0.f,0.f,0.f};
        #pragma unroll
        for (int r = 0; r < 4; ++r) { mrow[rf][r] = -1e30f; lrow[rf][r] = 0.f; }
    }

    char* Vts = lds + 32768;
    char* Pw  = lds + 49152 + w*8192;

    auto stageK = [&](int kv) {                    // K tile -> Ks[kv&1] (pre-swizzled src)
        char* dst = (kv & 1) ? (lds + 16384) : lds;
        const int s0 = kv << 7;
        #pragma unroll
        for (int c = 0; c < 4; ++c) {
            int o = c*4096 + tid*16;
            int row = o >> 7;
            int offl = (o & 127) ^ XSW(row);
            const char* ga = kb + (long)(s0 + row)*(3*E_*2) + offl;
            __builtin_amdgcn_global_load_lds(AS1V(ga), AS3V(dst + c*4096 + (tid >> 6)*1024), 16, 0, 0);
        }
    };
    auto stageV = [&](int kv) {                    // V^T tile -> Vts
        const int s0 = kv << 7;
        #pragma unroll
        for (int c = 0; c < 4; ++c) {
            int o = c*4096 + tid*16;
            int row = o >> 8;
            int offl = (o & 255) ^ XSW(row);
            const char* ga = vb + (long)row*(T_*2) + s0*2 + offl;
            __builtin_amdgcn_global_load_lds(AS1V(ga), AS3V(Vts + c*4096 + (tid >> 6)*1024), 16, 0, 0);
        }
    };

    stageK(0);
    WVM0; GBAR;                                    // K(0) resident everywhere

    for (int kv = 0; kv <= qt; ++kv) {
        GBAR;                                      // prior PV reads of Vts / old Ks done
        stageV(kv);
        if (kv < qt) stageK(kv + 1);
        const char* Kb = (kv & 1) ? (lds + 16384) : lds;

        // ---- QK^T (K resident from previous iteration's drain) ----
        f32x4 sacc[2][8];
        #pragma unroll
        for (int rf = 0; rf < 2; ++rf)
            #pragma unroll
            for (int cf = 0; cf < 8; ++cf) sacc[rf][cf] = (f32x4){0.f,0.f,0.f,0.f};
        __builtin_amdgcn_s_setprio(1);
        #pragma unroll
        for (int t = 0; t < 2; ++t) {
            bf16x8 kf[8];
            #pragma unroll
            for (int cf = 0; cf < 8; ++cf) {
                int srow = cf*16 + fr;
                kf[cf] = *(const bf16x8*)(Kb + srow*128 + ((t*64 + sel*16) ^ xs));
            }
            #pragma unroll
            for (int rf = 0; rf < 2; ++rf)
                #pragma unroll
                for (int cf = 0; cf < 8; ++cf)
                    sacc[rf][cf] = __builtin_amdgcn_mfma_f32_16x16x32_bf16(
                        qa[rf][t], kf[cf], sacc[rf][cf], 0, 0, 0);
        }
        __builtin_amdgcn_s_setprio(0);

        // ---- scale + causal mask + online softmax ----
        const bool diag = (kv == qt);
        const int s0 = kv << 7;
        #pragma unroll
        for (int rf = 0; rf < 2; ++rf)
            #pragma unroll
            for (int r = 0; r < 4; ++r) {
                int rowg = q0 + w*32 + rf*16 + sel*4 + r;
                float mx = -1e30f;
                #pragma unroll
                for (int cf = 0; cf < 8; ++cf) {
                    float v = sacc[rf][cf][r] * 0.03125f;
                    if (diag && (s0 + cf*16 + fr) > rowg) v = -1e30f;
                    sacc[rf][cf][r] = v;
                    mx = fmaxf(mx, v);
                }
                #pragma unroll
                for (int o = 1; o < 16; o <<= 1) mx = fmaxf(mx, __shfl_xor(mx, o));
                float mold = mrow[rf][r];
                float mnew = fmaxf(mold, mx);
                float alpha = __expf(mold - mnew);
                float sum = 0.f;
                #pragma unroll
                for (int cf = 0; cf < 8; ++cf) {
                    float p = __expf(sacc[rf][cf][r] - mnew);
                    sacc[rf][cf][r] = p;
                    sum += p;
                }
                #pragma unroll
                for (int o = 1; o < 16; o <<= 1) sum += __shfl_xor(sum, o);
                mrow[rf][r] = mnew;
                lrow[rf][r] = lrow[rf][r]*alpha + sum;
                #pragma unroll
                for (int cf = 0; cf < 4; ++cf) oacc[rf][cf][r] *= alpha;
            }

        // ---- P -> wave-private LDS (bf16, swizzled) ----
        #pragma unroll
        for (int rf = 0; rf < 2; ++rf)
            #pragma unroll
            for (int r = 0; r < 4; ++r) {
                int rl = rf*16 + sel*4 + r;
                char* base = Pw + rl*256;
                int sw = XSW(rl);
                #pragma unroll
                for (int cf = 0; cf < 8; ++cf)
                    *(u16*)(base + ((cf*32 + fr*2) ^ sw)) = f2bf(sacc[rf][cf][r]);
            }

        WVM0; GBAR;                                // V(kv) (+K(kv+1)) landed everywhere

        // ---- PV: O += P @ V ----
        __builtin_amdgcn_s_setprio(1);
        #pragma unroll
        for (int ts = 0; ts < 4; ++ts) {
            bf16x8 pa[2], vf[4];
            #pragma unroll
            for (int rf = 0; rf < 2; ++rf)
                pa[rf] = *(const bf16x8*)(Pw + (rf*16 + fr)*256 + ((ts*64 + sel*16) ^ xs));
            #pragma unroll
            for (int cf = 0; cf < 4; ++cf)
                vf[cf] = *(const bf16x8*)(Vts + (cf*16 + fr)*256 + ((ts*64 + sel*16) ^ xs));
            #pragma unroll
            for (int rf = 0; rf < 2; ++rf)
                #pragma unroll
                for (int cf = 0; cf < 4; ++cf)
                    oacc[rf][cf] = __builtin_amdgcn_mfma_f32_16x16x32_bf16(
                        pa[rf], vf[cf], oacc[rf][cf], 0, 0, 0);
        }
        __builtin_amdgcn_s_setprio(0);
    }

    u16* ab = attno + ((long)b*T_ + q0 + w*32)*E_ + (size_t)hh*HD_;
    #pragma unroll
    for (int rf = 0; rf < 2; ++rf)
        #pragma unroll
        for (int r = 0; r < 4; ++r) {
            float rinv = 1.f / lrow[rf][r];
            int rl = rf*16 + sel*4 + r;
            #pragma unroll
            for (int cf = 0; cf < 4; ++cf)
                ab[(long)rl*E_ + cf*16 + fr] = f2bf(oacc[rf][cf][r] * rinv);
        }
}

// ---------------- 64x128 BK=64 dbuf GEMM, 32x32x16 MFMA + XSW32: f32 = acc+bias+res ------
__global__ __launch_bounds__(256, 2)
void k_gemmM64(const u16* __restrict__ A, const u16* __restrict__ Bt,
               float* __restrict__ C, const float* __restrict__ bias,
               const float* __restrict__ res,
               long lda, long ldb, long ldc, int Kk, int nTM)
{
    __shared__ alignas(128) char lds[49152];
    const int wg = xcd_swz(blockIdx.x, gridDim.x);
    const int m0 = (wg % nTM) << 6, n0 = (wg / nTM) << 7;

    const int tid = threadIdx.x, wid = tid >> 6, lane = tid & 63;
    const int l31 = lane & 31, khi = (lane >> 5) << 4;
    const int wr = wid >> 1, wc = wid & 1;
    const int KT = Kk >> 6;

    const long lda2 = lda*2, ldb2 = ldb*2;
    const int rowL = tid >> 3;                         // 0..31
    const int col7 = (tid & 7) << 4;                   // 16B slot within 128B row
    const char* pA = (const char*)A + ((long)m0)*lda2;
    const char* pB = (const char*)Bt + ((long)n0)*ldb2;
    char* ldwA = lds + (wid << 10);
    char* ldwB = lds + 16384 + (wid << 10);

    auto stageA = [&](int kt) {                        // 2 loads: rows 0..63
        const int d = (kt & 1) << 13;
        const long kb = (long)kt << 7;
        #pragma unroll
        for (int c = 0; c < 2; ++c) {
            const int row = rowL + (c << 5);
            const int offl = col7 ^ XSW32(row);
            __builtin_amdgcn_global_load_lds(AS1V(pA + (long)row*lda2 + kb + offl),
                                             AS3V(ldwA + d + (c << 12)), 16, 0, 0);
        }
    };
    auto stageB = [&](int kt) {                        // 4 loads: rows 0..127
        const int d = (kt & 1) << 14;
        const long kb = (long)kt << 7;
        #pragma unroll
        for (int c = 0; c < 4; ++c) {
            const int row = rowL + (c << 5);
            const int offl = col7 ^ XSW32(row);
            __builtin_amdgcn_global_load_lds(AS1V(pB + (long)row*ldb2 + kb + offl),
                                             AS3V(ldwB + d + (c << 12)), 16, 0, 0);
        }
    };

    f32x16 acc[2];
    #pragma unroll
    for (int j = 0; j < 2; ++j)
        #pragma unroll
        for (int e = 0; e < 16; ++e) acc[j][e] = 0.f;

    stageA(0); stageB(0); stageA(1); stageB(1);
    WVM6; GBAR;

    for (int t = 0; t < KT; ++t) {
        const int dA = (t & 1) << 13, dB = (t & 1) << 14;
        bf16x8 a[4], b[2][4];
        {
            const int row = wr*32 + l31;               // wave's 32 A rows
            const int sw = XSW32(row);
            const int base = dA + (row << 7);
            #pragma unroll
            for (int tt = 0; tt < 4; ++tt)
                a[tt] = *(const bf16x8*)(lds + base + ((khi + (tt << 5)) ^ sw));
        }
        #pragma unroll
        for (int ch = 0; ch < 2; ++ch) {
            const int row = wc*64 + ch*32 + l31;       // wave's B cols
            const int sw = XSW32(row);
            const int base = 16384 + dB + (row << 7);
            #pragma unroll
            for (int tt = 0; tt < 4; ++tt)
                b[ch][tt] = *(const bf16x8*)(lds + base + ((khi + (tt << 5)) ^ sw));
        }
        __builtin_amdgcn_s_setprio(1);
        #pragma unroll
        for (int ch = 0; ch < 2; ++ch)
            #pragma unroll
            for (int tt = 0; tt < 4; ++tt)
                acc[ch] = __builtin_amdgcn_mfma_f32_32x32x16_bf16(
                    a[tt], b[ch][tt], acc[ch], 0, 0, 0);
        __builtin_amdgcn_s_setprio(0);
        GBAR;                               // all waves' reads of buf d complete
        if (t + 2 < KT) {
            stageA(t+2); stageB(t+2);       // overwrite buf d (t+2 has same parity)
            WVM6;                           // wait stage(t+1): 6 newer in flight
        } else {
            WVM0;                           // tail: drain everything
        }
        GBAR;
    }

    // epilogue: 32x32 C/D map: col = l31, row = (r&3) + 8*(r>>2) + 4*(lane>>5)
    const int rowAdd = ((lane >> 5) << 2);
    #pragma unroll
    for (int r = 0; r < 16; ++r) {
        const int row = m0 + wr*32 + (r & 3) + ((r >> 2) << 3) + rowAdd;
        const long rbase = (long)row * ldc;
        #pragma unroll
        for (int ch = 0; ch < 2; ++ch) {
            const int col = n0 + wc*64 + ch*32 + l31;
            long idx = rbase + col;
            C[idx] = acc[ch][r] + bias[col] + res[idx];
        }
    }
}

// ================= 256x256 MFMA GEMM — merged-phase, 32x32x16 + XSW32 (R16, frozen) =====
// MODE: 0 bf16-out ; 2 bf16 gelu(acc+bias) ; 4 f32 acc+bias
template<int MODE>
__global__ __launch_bounds__(512, 2)
void k_gemm256(const u16* __restrict__ A, const u16* __restrict__ Bt,
               void* __restrict__ Cv, const float* __restrict__ bias,
               long lda, long ldb, long ldc, int Kk, int nTM)
{
    __shared__ alignas(128) char lds[131072];
    const int wg = xcd_swz(blockIdx.x, gridDim.x);
    const int m0 = (wg % nTM) << 8, n0 = (wg / nTM) << 8;

    const int tid = threadIdx.x, wid = tid >> 6, lane = tid & 63;
    const int l31 = lane & 31, khi = (lane >> 5) << 4;   // 32x32 frag: row/col, k-byte half
    const int wr = wid >> 2, wc = wid & 3;
    const int KT = Kk >> 6;

    const char* Asrc = (const char*)A + (long)m0 * lda * 2;
    const char* Bsrc = (const char*)Bt + (long)n0 * ldb * 2;

    auto stage = [&](int mat, int h, int kt) {
        const int d = kt & 1;
        const int kc = kt < KT ? kt : KT - 1;
        const char* src = mat ? Bsrc : Asrc;
        const long ldd = (mat ? ldb : lda) * 2;
        const long kbyte = (long)kc << 7;
        const int mo = mat << 16;
        #pragma unroll
        for (int q = 0; q < 2; ++q) {
            const int o = (h << 14) + (q << 13) + tid*16;       // linear byte in buffer
            const int row = o >> 7;
            const int offl = (o & 127) ^ XSW32(row);            // pre-swizzled source
            const char* ga = src + (long)row*ldd + kbyte + offl;
            char* ldst = lds + mo + (d << 15) + (h << 14) + (q << 13) + (wid << 10);
            __builtin_amdgcn_global_load_lds(AS1V(ga), AS3V(ldst), 16, 0, 0);
        }
    };

    bf16x8 a[2][4], b[2][4];                    // a: 2 row-blocks x 4 k-steps; b: 2 ch x 4
    f32x16 acc[4][2];                           // 4 row-blocks(32) x 2 col-blocks(32)
    #pragma unroll
    for (int i = 0; i < 4; ++i)
        #pragma unroll
        for (int j = 0; j < 2; ++j)
            #pragma unroll
            for (int e = 0; e < 16; ++e) acc[i][j][e] = 0.f;

    auto readA = [&](int d, int rh) {           // rows wr*128 + rh*64 + rb*32 + l31
        const int rowb = wr*128 + rh*64 + l31;
        #pragma unroll
        for (int rb = 0; rb < 2; ++rb) {
            const int row = rowb + (rb << 5);
            const int sw = XSW32(row);
            const int base = (d << 15) + (row << 7);
            #pragma unroll
            for (int t = 0; t < 4; ++t)
                a[rb][t] = *(const bf16x8*)(lds + base + ((khi + (t << 5)) ^ sw));
        }
    };
    auto readB = [&](int d, int ch) {           // cols wc*64 + ch*32 + l31
        const int row = wc*64 + ch*32 + l31;
        const int sw = XSW32(row);
        const int base = 65536 + (d << 15) + (row << 7);
        #pragma unroll
        for (int t = 0; t < 4; ++t)
            b[ch][t] = *(const bf16x8*)(lds + base + ((khi + (t << 5)) ^ sw));
    };
    auto mfma32 = [&](int rh, int ch) {
        __builtin_amdgcn_s_setprio(1);
        #pragma unroll
        for (int rb = 0; rb < 2; ++rb)
            #pragma unroll
            for (int t = 0; t < 4; ++t)
                acc[rh*2+rb][ch] = __builtin_amdgcn_mfma_f32_32x32x16_bf16(
                    a[rb][t], b[ch][t], acc[rh*2+rb][ch], 0, 0, 0);
        __builtin_amdgcn_s_setprio(0);
    };

    // prologue: fully stage K-tiles 0 (buf0) and 1 (buf1)
    stage(0,0,0); stage(0,1,0); stage(1,0,0); stage(1,1,0);
    stage(0,0,1); stage(0,1,1); stage(1,0,1); stage(1,1,1);
    WVM4; GBAR;

    for (int kt = 0; kt < KT; kt += 2) {
        // merged ph0+1: A-half0 + both B col-blocks of buf0; stage A(kt+1)
        readA(0,0); readB(0,0); readB(0,1); stage(0,0,kt+1); stage(0,1,kt+1);
        GBAR; mfma32(0,0); mfma32(0,1); WLG0; GBAR;
        // merged ph2+3: A-half1; stage B(kt+2); gate: tile kt+1 landed
        readA(0,1); stage(1,0,kt+2); stage(1,1,kt+2);
        GBAR; mfma32(1,1); mfma32(1,0); WLG0; WVM4; GBAR;
        // merged ph4+5: buf1 A-half0 + both B col-blocks; stage A(kt+2)
        readA(1,0); readB(1,0); readB(1,1); stage(0,0,kt+2); stage(0,1,kt+2);
        GBAR; mfma32(0,0); mfma32(0,1); WLG0; GBAR;
        // merged ph6+7: A-half1; stage B(kt+3); gate: tile kt+2 landed
        readA(1,1); stage(1,0,kt+3); stage(1,1,kt+3);
        GBAR; mfma32(1,1); mfma32(1,0); WLG0; WVM4; GBAR;
    }

    // epilogue: 32x32 C/D map: col = l31, row = (r&3) + 8*(r>>2) + 4*(lane>>5)
    const int rowAdd = ((lane >> 5) << 2);
    #pragma unroll
    for (int i = 0; i < 4; ++i) {
        #pragma unroll
        for (int r = 0; r < 16; ++r) {
            const int row = m0 + wr*128 + i*32 + (r & 3) + ((r >> 2) << 3) + rowAdd;
            const long rbase = (long)row * ldc;
            #pragma unroll
            for (int ch = 0; ch < 2; ++ch) {
                const int col = n0 + wc*64 + ch*32 + l31;
                float v = acc[i][ch][r];
                if constexpr (MODE == 0) {
                    ((u16*)Cv)[rbase + col] = f2bf(v);
                } else if constexpr (MODE == 2) {
                    float tt = v + bias[col];
                    ((u16*)Cv)[rbase + col] = f2bf(tt * 0.5f * (1.f + erff(tt * 0.70710678118f)));
                } else {
                    ((float*)Cv)[rbase + col] = v + bias[col];
                }
            }
        }
    }
}

extern "C" void kernel_launch(void* const* d_in, const int* in_sizes, int n_in,
                              void* d_out, int out_size, void* d_ws, size_t ws_size,
                              hipStream_t stream)
{
    (void)in_sizes; (void)n_in; (void)out_size; (void)ws_size;
    const int*   x   = (const int*)  d_in[0];
    const float* tok = (const float*)d_in[1];
    const float* pos = (const float*)d_in[2];
    const float* Wq  = (const float*)d_in[3];
    const float* Wk  = (const float*)d_in[4];
    const float* Wv  = (const float*)d_in[5];
    const float* Wp  = (const float*)d_in[6];
    const float* bp  = (const float*)d_in[7];
    const float* g1  = (const float*)d_in[8];
    const float* bb1 = (const float*)d_in[9];
    const float* g2  = (const float*)d_in[10];
    const float* bb2 = (const float*)d_in[11];
    const float* W1  = (const float*)d_in[12];
    const float* b1  = (const float*)d_in[13];
    const float* W2  = (const float*)d_in[14];
    const float* b2  = (const float*)d_in[15];
    const float* gF  = (const float*)d_in[16];
    const float* bF  = (const float*)d_in[17];
    const float* Wo  = (const float*)d_in[18];
    const float* bo  = (const float*)d_in[19];
    float* out = (float*)d_out;

    char* wsp = (char*)d_ws;
    auto alloc = [&](size_t bytes) { char* p = wsp; wsp += (bytes + 255) & ~(size_t)255; return p; };
    u16* WqkvT  = (u16*)alloc((size_t)L_*3*E_*E_*2);
    u16* WprojT = (u16*)alloc((size_t)L_*E_*E_*2);
    u16* W1T    = (u16*)alloc((size_t)L_*FF_*E_*2);
    u16* W2T    = (u16*)alloc((size_t)L_*E_*FF_*2);
    u16* WoutT  = (u16*)alloc((size_t)V_*E_*2);
    float* h    = (float*)alloc((size_t)M_*E_*4);
    u16* xn     = (u16*)alloc((size_t)M_*E_*2);
    u16* qkv    = (u16*)alloc((size_t)M_*3*E_*2);
    u16* vt     = (u16*)alloc((size_t)B_*H_*HD_*T_*2);
    u16* attno  = (u16*)alloc((size_t)M_*E_*2);
    u16* ffb    = (u16*)alloc((size_t)M_*FF_*2);

    dim3 tb(32, 8);
    k_packqkv<<<dim3(HD_/32, E_/32, 3*L_*H_), tb, 0, stream>>>(Wq, Wk, Wv, WqkvT);
    k_transpose<float><<<dim3(E_/32, E_/32, L_), tb, 0, stream>>>(
        Wp, WprojT, E_, E_, (long)E_, (long)E_, 1, (long)E_*E_, 0, (long)E_*E_, 0);
    k_transpose<float><<<dim3(FF_/32, E_/32, L_), tb, 0, stream>>>(
        W1, W1T, E_, FF_, (long)FF_, (long)E_, 1, (long)E_*FF_, 0, (long)FF_*E_, 0);
    k_transpose<float><<<dim3(E_/32, FF_/32, L_), tb, 0, stream>>>(
        W2, W2T, FF_, E_, (long)E_, (long)FF_, 1, (long)FF_*E_, 0, (long)E_*FF_, 0);
    k_transpose<float><<<dim3(V_/32, E_/32, 1), tb, 0, stream>>>(
        Wo, WoutT, E_, V_, (long)V_, (long)E_, 1, 0, 0, 0, 0);
    k_embed<<<dim3(M_*E_/4/256), dim3(256), 0, stream>>>(x, tok, pos, h);

    auto gemm256 = [&](int mode, const u16* A, const u16* Bt, void* C, const float* bias,
                       int Mm, int Nn, int Kk, long lda, long ldb, long ldc) {
        int nTM = Mm >> 8;
        dim3 g(nTM * (Nn >> 8)), blk(512);
        switch (mode) {
        case 0: k_gemm256<0><<<g, blk, 0, stream>>>(A, Bt, C, bias, lda, ldb, ldc, Kk, nTM); break;
        case 2: k_gemm256<2><<<g, blk, 0, stream>>>(A, Bt, C, bias, lda, ldb, ldc, Kk, nTM); break;
        case 4: k_gemm256<4><<<g, blk, 0, stream>>>(A, Bt, C, bias, lda, ldb, ldc, Kk, nTM); break;
        }
    };

    for (int l = 0; l < L_; ++l) {
        k_ln<<<dim3(M_), dim3(256), 0, stream>>>(h, g1 + (size_t)l*E_, bb1 + (size_t)l*E_, xn);
        gemm256(0, xn, WqkvT + (size_t)l*3*E_*E_, qkv, nullptr,
                M_, 3*E_, E_, (long)E_, (long)E_, (long)3*E_);
        k_transpose<u16><<<dim3(HD_/32, T_/32, B_*H_), tb, 0, stream>>>(
            qkv + 2*E_, vt, T_, HD_, (long)3*E_, (long)T_,
            H_, (long)T_*3*E_, (long)HD_, (long)H_*HD_*T_, (long)HD_*T_);
        k_flash<<<dim3(B_*H_*8), dim3(256), 0, stream>>>(qkv, vt, attno);
        k_gemmM64<<<dim3((M_/64)*(E_/128)), dim3(256), 0, stream>>>(
            attno, WprojT + (size_t)l*E_*E_, h, bp + (size_t)l*E_, h,
            (long)E_, (long)E_, (long)E_, E_, M_/64);
        k_ln<<<dim3(M_), dim3(256), 0, stream>>>(h, g2 + (size_t)l*E_, bb2 + (size_t)l*E_, xn);
        gemm256(2, xn, W1T + (size_t)l*FF_*E_, ffb, b1 + (size_t)l*FF_,
                M_, FF_, E_, (long)E_, (long)E_, (long)FF_);
        k_gemmM64<<<dim3((M_/64)*(E_/128)), dim3(256), 0, stream>>>(
            ffb, W2T + (size_t)l*E_*FF_, h, b2 + (size_t)l*E_, h,
            (long)FF_, (long)FF_, (long)E_, FF_, M_/64);
    }
    k_ln<<<dim3(M_), dim3(256), 0, stream>>>(h, gF, bF, xn);
    gemm256(4, xn, WoutT, out, bo, M_, V_, E_, (long)E_, (long)E_, (long)V_);
}

// Round 19
// 2685.264 us; speedup vs baseline: 1.0037x; 1.0037x over previous
//
#include <hip/hip_runtime.h>

#define B_ 4
#define T_ 1024
#define E_ 1024
#define H_ 16
#define HD_ 64
#define L_ 8
#define V_ 32000
#define FF_ 4096
#define M_ (B_*T_)

typedef unsigned short u16;
typedef __attribute__((ext_vector_type(8))) short bf16x8;   // 8 bf16 = 4 VGPR
typedef __attribute__((ext_vector_type(4))) float f32x4;
typedef __attribute__((ext_vector_type(16))) float f32x16;

#define AS1V(p) ((__attribute__((address_space(1))) void*)(p))
#define AS3V(p) ((__attribute__((address_space(3))) void*)(p))
#define XSW(row) (((row) & 7) << 4)
#define XSW32(row) ((((row) ^ ((row) >> 3)) & 7) << 4)

#define GBAR  asm volatile("s_barrier" ::: "memory")
#define WLG0  asm volatile("s_waitcnt lgkmcnt(0)" ::: "memory")
#define WVM4  asm volatile("s_waitcnt vmcnt(4)" ::: "memory")
#define WVM6  asm volatile("s_waitcnt vmcnt(6)" ::: "memory")
#define WVM0  asm volatile("s_waitcnt vmcnt(0)" ::: "memory")

__device__ __forceinline__ u16 f2bf(float f) {              // RNE f32->bf16
    unsigned int u = __float_as_uint(f);
    u += 0x7FFFu + ((u >> 16) & 1u);
    return (u16)(u >> 16);
}
__device__ __forceinline__ float bf2f(u16 v) {
    return __uint_as_float(((unsigned int)v) << 16);
}
__device__ __forceinline__ float ldf(const float* p, long i) { return p[i]; }
__device__ __forceinline__ float ldf(const u16*   p, long i) { return bf2f(p[i]); }

// bijective XCD swizzle (m204): nwg workgroups -> chunk per XCD
__device__ __forceinline__ int xcd_swz(int orig, int nwg) {
    int q8 = nwg >> 3, r8 = nwg & 7;
    int xcd = orig & 7, sub = orig >> 3;
    return (xcd < r8 ? xcd*(q8+1) : r8*(q8+1) + (xcd-r8)*q8) + sub;
}

// ---------------- batched tiled transpose:  dst[N][K](bf16) = src[K][N] ----------------
template<typename ST>
__global__ void k_transpose(const ST* __restrict__ src, u16* __restrict__ dst,
                            int K, int N, long srs, long drs,
                            int ZH, long szb, long szh, long dzb, long dzh)
{
    __shared__ float tile[32][33];
    int z = blockIdx.z; int zb = z / ZH, zh = z % ZH;
    const ST* s = src + (long)zb*szb + (long)zh*szh;
    u16* d = dst + (long)zb*dzb + (long)zh*dzh;
    int k0 = blockIdx.y * 32, n0 = blockIdx.x * 32;
    int tx = threadIdx.x, ty = threadIdx.y;
    for (int i = ty; i < 32; i += 8) {
        int k = k0 + i, n = n0 + tx;
        tile[i][tx] = (k < K && n < N) ? ldf(s, (long)k*srs + n) : 0.f;
    }
    __syncthreads();
    for (int i = ty; i < 32; i += 8) {
        int n = n0 + i, k = k0 + tx;
        if (n < N && k < K) d[(long)n*drs + k] = f2bf(tile[tx][i]);
    }
}

// ---------------- merged QKV weight pack: Wq/Wk/Wv [L,H,E,HD] -> WqkvT [L][3E][E] ------
__global__ void k_packqkv(const float* __restrict__ Wq, const float* __restrict__ Wk,
                          const float* __restrict__ Wv, u16* __restrict__ dst)
{
    __shared__ float tile[32][33];
    int z = blockIdx.z;                 // 0 .. 3*L*H-1
    int s = z / (L_*H_);
    int lh = z % (L_*H_);
    int l = lh / H_, hh = lh % H_;
    const float* W = (s == 0 ? Wq : (s == 1 ? Wk : Wv));
    const float* src = W + ((long)l*H_ + hh)*(long)E_*HD_;   // [E][HD]
    u16* d = dst + ((size_t)l*3*E_ + (size_t)s*E_ + (size_t)hh*HD_) * E_;
    int k0 = blockIdx.y * 32, n0 = blockIdx.x * 32;          // k over E, n over HD
    int tx = threadIdx.x, ty = threadIdx.y;
    for (int i = ty; i < 32; i += 8)
        tile[i][tx] = src[(long)(k0 + i)*HD_ + n0 + tx];
    __syncthreads();
    for (int i = ty; i < 32; i += 8)
        d[(long)(n0 + i)*E_ + k0 + tx] = f2bf(tile[tx][i]);
}

// ---------------- token+pos embedding -> h (f32) ----------------
__global__ void k_embed(const int* __restrict__ x, const float* __restrict__ tok,
                        const float* __restrict__ pos, float* __restrict__ h)
{
    long i = (long)blockIdx.x * 256 + threadIdx.x;
    int e4 = (int)(i & (E_/4 - 1));
    long bt = i >> 8;
    int t = (int)(bt & (T_ - 1));
    int id = x[bt];
    float4 a = *(const float4*)(tok + (long)id*E_ + e4*4);
    float4 p = *(const float4*)(pos + (long)t*E_ + e4*4);
    float4 o; o.x=a.x+p.x; o.y=a.y+p.y; o.z=a.z+p.z; o.w=a.w+p.w;
    *(float4*)(h + bt*E_ + e4*4) = o;
}

// ---------------- layernorm (row of E=1024, block=256) -> bf16 ----------------
__global__ void k_ln(const float* __restrict__ in, const float* __restrict__ g,
                     const float* __restrict__ b, u16* __restrict__ out)
{
    int row = blockIdx.x, tid = threadIdx.x;
    float4 v = *(const float4*)(in + (long)row*E_ + tid*4);
    float s = v.x + v.y + v.z + v.w;
    float ss = v.x*v.x + v.y*v.y + v.z*v.z + v.w*v.w;
    #pragma unroll
    for (int o = 32; o; o >>= 1) { s += __shfl_down(s, o); ss += __shfl_down(ss, o); }
    __shared__ float r0[4], r1[4];
    if ((tid & 63) == 0) { r0[tid >> 6] = s; r1[tid >> 6] = ss; }
    __syncthreads();
    s  = r0[0] + r0[1] + r0[2] + r0[3];
    ss = r1[0] + r1[1] + r1[2] + r1[3];
    float mean = s * (1.f/E_);
    float rstd = rsqrtf(ss * (1.f/E_) - mean*mean + 1e-5f);
    float4 gv = *(const float4*)(g + tid*4);
    float4 bv = *(const float4*)(b + tid*4);
    ushort4 pk;
    pk.x = f2bf((v.x - mean)*rstd*gv.x + bv.x);
    pk.y = f2bf((v.y - mean)*rstd*gv.y + bv.y);
    pk.z = f2bf((v.z - mean)*rstd*gv.z + bv.z);
    pk.w = f2bf((v.w - mean)*rstd*gv.w + bv.w);
    *(ushort4*)(out + (long)row*E_ + tid*4) = pk;
}

// ---------------- flash attention: Q-tile 128 x KV-tiles 128, online softmax ----------
__global__ __launch_bounds__(256, 2)
void k_flash(const u16* __restrict__ qkv, const u16* __restrict__ vt,
             u16* __restrict__ attno)
{
    __shared__ alignas(16) char lds[65536];
    const int wg = xcd_swz(blockIdx.x, gridDim.x);
    const int bh = wg >> 3, qt = 7 - (wg & 7);      // heavy q-tiles first
    const int b = bh >> 4, hh = bh & 15;

    const int tid = threadIdx.x, w = tid >> 6, lane = tid & 63;
    const int fr = lane & 15, sel = lane >> 4;
    const int xs = XSW(fr);

    const char* qb = (const char*)(qkv + (long)b*T_*3*E_ + (size_t)hh*HD_);
    const char* kb = (const char*)(qkv + (long)b*T_*3*E_ + E_ + (size_t)hh*HD_);
    const char* vb = (const char*)(vt + (size_t)bh*HD_*T_);
    const int q0 = qt << 7;

    bf16x8 qa[2][2];
    #pragma unroll
    for (int rf = 0; rf < 2; ++rf)
        #pragma unroll
        for (int t = 0; t < 2; ++t) {
            int row = q0 + w*32 + rf*16 + fr;
            qa[rf][t] = *(const bf16x8*)(qb + (long)row*(3*E_*2) + t*64 + sel*16);
        }

    f32x4 oacc[2][4];
    float mrow[2][4], lrow[2][4];
    #pragma unroll
    for (int rf = 0; rf < 2; ++rf) {
        #pragma unroll
        for (int cf = 0; cf < 4; ++cf) oacc[rf][cf] = (f32x4){0.f,0.f,0.f,0.f};
        #pragma unroll
        for (int r = 0; r < 4; ++r) { mrow[rf][r] = -1e30f; lrow[rf][r] = 0.f; }
    }

    char* Ks  = lds;
    char* Vts = lds + 16384;
    char* Pw  = lds + 32768 + w*8192;

    for (int kv = 0; kv <= qt; ++kv) {
        const int s0 = kv << 7;
        __syncthreads();
        #pragma unroll
        for (int c = 0; c < 4; ++c) {              // K tile -> Ks (pre-swizzled source)
            int o = c*4096 + tid*16;
            int row = o >> 7;
            int offl = (o & 127) ^ XSW(row);
            const char* ga = kb + (long)(s0 + row)*(3*E_*2) + offl;
            __builtin_amdgcn_global_load_lds(AS1V(ga), AS3V(Ks + c*4096 + (tid >> 6)*1024), 16, 0, 0);
        }
        #pragma unroll
        for (int c = 0; c < 4; ++c) {              // V^T tile -> Vts
            int o = c*4096 + tid*16;
            int row = o >> 8;
            int offl = (o & 255) ^ XSW(row);
            const char* ga = vb + (long)row*(T_*2) + s0*2 + offl;
            __builtin_amdgcn_global_load_lds(AS1V(ga), AS3V(Vts + c*4096 + (tid >> 6)*1024), 16, 0, 0);
        }
        __syncthreads();

        // ---- QK^T ----
        f32x4 sacc[2][8];
        #pragma unroll
        for (int rf = 0; rf < 2; ++rf)
            #pragma unroll
            for (int cf = 0; cf < 8; ++cf) sacc[rf][cf] = (f32x4){0.f,0.f,0.f,0.f};
        __builtin_amdgcn_s_setprio(1);
        #pragma unroll
        for (int t = 0; t < 2; ++t) {
            bf16x8 kf[8];
            #pragma unroll
            for (int cf = 0; cf < 8; ++cf) {
                int srow = cf*16 + fr;
                kf[cf] = *(const bf16x8*)(Ks + srow*128 + ((t*64 + sel*16) ^ xs));
            }
            #pragma unroll
            for (int rf = 0; rf < 2; ++rf)
                #pragma unroll
                for (int cf = 0; cf < 8; ++cf)
                    sacc[rf][cf] = __builtin_amdgcn_mfma_f32_16x16x32_bf16(
                        qa[rf][t], kf[cf], sacc[rf][cf], 0, 0, 0);
        }
        __builtin_amdgcn_s_setprio(0);

        // ---- scale + causal mask + online softmax ----
        const bool diag = (kv == qt);
        #pragma unroll
        for (int rf = 0; rf < 2; ++rf)
            #pragma unroll
            for (int r = 0; r < 4; ++r) {
                int rowg = q0 + w*32 + rf*16 + sel*4 + r;
                float mx = -1e30f;
                #pragma unroll
                for (int cf = 0; cf < 8; ++cf) {
                    float v = sacc[rf][cf][r] * 0.03125f;
                    if (diag && (s0 + cf*16 + fr) > rowg) v = -1e30f;
                    sacc[rf][cf][r] = v;
                    mx = fmaxf(mx, v);
                }
                #pragma unroll
                for (int o = 1; o < 16; o <<= 1) mx = fmaxf(mx, __shfl_xor(mx, o));
                float mold = mrow[rf][r];
                float mnew = fmaxf(mold, mx);
                float alpha = __expf(mold - mnew);
                float sum = 0.f;
                #pragma unroll
                for (int cf = 0; cf < 8; ++cf) {
                    float p = __expf(sacc[rf][cf][r] - mnew);
                    sacc[rf][cf][r] = p;
                    sum += p;
                }
                #pragma unroll
                for (int o = 1; o < 16; o <<= 1) sum += __shfl_xor(sum, o);
                mrow[rf][r] = mnew;
                lrow[rf][r] = lrow[rf][r]*alpha + sum;
                #pragma unroll
                for (int cf = 0; cf < 4; ++cf) oacc[rf][cf][r] *= alpha;
            }

        // ---- P -> wave-private LDS (bf16, swizzled) ----
        #pragma unroll
        for (int rf = 0; rf < 2; ++rf)
            #pragma unroll
            for (int r = 0; r < 4; ++r) {
                int rl = rf*16 + sel*4 + r;
                char* base = Pw + rl*256;
                int sw = XSW(rl);
                #pragma unroll
                for (int cf = 0; cf < 8; ++cf)
                    *(u16*)(base + ((cf*32 + fr*2) ^ sw)) = f2bf(sacc[rf][cf][r]);
            }

        // ---- PV: O += P @ V ----
        __builtin_amdgcn_s_setprio(1);
        #pragma unroll
        for (int ts = 0; ts < 4; ++ts) {
            bf16x8 pa[2], vf[4];
            #pragma unroll
            for (int rf = 0; rf < 2; ++rf)
                pa[rf] = *(const bf16x8*)(Pw + (rf*16 + fr)*256 + ((ts*64 + sel*16) ^ xs));
            #pragma unroll
            for (int cf = 0; cf < 4; ++cf)
                vf[cf] = *(const bf16x8*)(Vts + (cf*16 + fr)*256 + ((ts*64 + sel*16) ^ xs));
            #pragma unroll
            for (int rf = 0; rf < 2; ++rf)
                #pragma unroll
                for (int cf = 0; cf < 4; ++cf)
                    oacc[rf][cf] = __builtin_amdgcn_mfma_f32_16x16x32_bf16(
                        pa[rf], vf[cf], oacc[rf][cf], 0, 0, 0);
        }
        __builtin_amdgcn_s_setprio(0);
    }

    u16* ab = attno + ((long)b*T_ + q0 + w*32)*E_ + (size_t)hh*HD_;
    #pragma unroll
    for (int rf = 0; rf < 2; ++rf)
        #pragma unroll
        for (int r = 0; r < 4; ++r) {
            float rinv = 1.f / lrow[rf][r];
            int rl = rf*16 + sel*4 + r;
            #pragma unroll
            for (int cf = 0; cf < 4; ++cf)
                ab[(long)rl*E_ + cf*16 + fr] = f2bf(oacc[rf][cf][r] * rinv);
        }
}

// ---------------- 64x128 BK=64 dbuf swizzled GEMM: f32 = acc + bias + res ----------------
// BM=64 -> grid 512 blocks -> 2 blocks/CU, re-read counts unchanged vs 128x128.
__global__ __launch_bounds__(256, 2)
void k_gemmM64(const u16* __restrict__ A, const u16* __restrict__ Bt,
               float* __restrict__ C, const float* __restrict__ bias,
               const float* __restrict__ res,
               long lda, long ldb, long ldc, int Kk, int nTM)
{
    __shared__ alignas(128) char lds[49152];
    const int wg = xcd_swz(blockIdx.x, gridDim.x);
    const int m0 = (wg % nTM) << 6, n0 = (wg / nTM) << 7;

    const int tid = threadIdx.x, wid = tid >> 6, lane = tid & 63;
    const int fr = lane & 15, sel = lane >> 4;
    const int wr = wid >> 1, wc = wid & 1;
    const int xs = XSW(fr);
    const int KT = Kk >> 6;

    const long lda2 = lda*2, ldb2 = ldb*2;
    const int rowL = tid >> 3;                         // 0..31
    const int offl = (((tid & 7) ^ (rowL & 7)) << 4);  // pre-swizzled src offset
    const char* pA = (const char*)A + ((long)(m0 + rowL))*lda2 + offl;
    const char* pB = (const char*)Bt + ((long)(n0 + rowL))*ldb2 + offl;
    char* ldwA = lds + (wid << 10);
    char* ldwB = lds + 16384 + (wid << 10);

    auto stageA = [&](int kt) {                        // 2 loads: rows 0..63
        const int d = (kt & 1) << 13;
        const long kb = (long)kt << 7;
        #pragma unroll
        for (int c = 0; c < 2; ++c)
            __builtin_amdgcn_global_load_lds(AS1V(pA + (long)(c << 5)*lda2 + kb),
                                             AS3V(ldwA + d + (c << 12)), 16, 0, 0);
    };
    auto stageB = [&](int kt) {                        // 4 loads: rows 0..127
        const int d = (kt & 1) << 14;
        const long kb = (long)kt << 7;
        #pragma unroll
        for (int c = 0; c < 4; ++c)
            __builtin_amdgcn_global_load_lds(AS1V(pB + (long)(c << 5)*ldb2 + kb),
                                             AS3V(ldwB + d + (c << 12)), 16, 0, 0);
    };

    f32x4 acc[2][4];
    #pragma unroll
    for (int i = 0; i < 2; ++i)
        #pragma unroll
        for (int j = 0; j < 4; ++j) acc[i][j] = (f32x4){0.f,0.f,0.f,0.f};

    stageA(0); stageB(0); stageA(1); stageB(1);
    WVM6; GBAR;

    for (int t = 0; t < KT; ++t) {
        const int dA = (t & 1) << 13, dB = (t & 1) << 14;
        bf16x8 a[2][2], b[4][2];
        #pragma unroll
        for (int m = 0; m < 2; ++m)
            #pragma unroll
            for (int tt = 0; tt < 2; ++tt)
                a[m][tt] = *(const bf16x8*)(lds + dA +
                    (((wr*32 + m*16 + fr) << 7) + ((sel*16 + tt*64) ^ xs)));
        #pragma unroll
        for (int n = 0; n < 4; ++n)
            #pragma unroll
            for (int tt = 0; tt < 2; ++tt)
                b[n][tt] = *(const bf16x8*)(lds + 16384 + dB +
                    (((wc*64 + n*16 + fr) << 7) + ((sel*16 + tt*64) ^ xs)));
        __builtin_amdgcn_s_setprio(1);
        #pragma unroll
        for (int m = 0; m < 2; ++m)
            #pragma unroll
            for (int n = 0; n < 4; ++n)
                #pragma unroll
                for (int tt = 0; tt < 2; ++tt)
                    acc[m][n] = __builtin_amdgcn_mfma_f32_16x16x32_bf16(
                        a[m][tt], b[n][tt], acc[m][n], 0, 0, 0);
        __builtin_amdgcn_s_setprio(0);
        GBAR;                               // all waves' reads of buf d complete
        if (t + 2 < KT) {
            stageA(t+2); stageB(t+2);       // overwrite buf d (t+2 has same parity)
            WVM6;                           // wait stage(t+1): 6 newer in flight
        } else {
            WVM0;                           // tail: drain everything
        }
        GBAR;
    }

    #pragma unroll
    for (int m = 0; m < 2; ++m) {
        #pragma unroll
        for (int rr = 0; rr < 4; ++rr) {
            const int row = m0 + wr*32 + m*16 + sel*4 + rr;
            #pragma unroll
            for (int n = 0; n < 4; ++n) {
                const int col = n0 + wc*64 + n*16 + fr;
                long idx = (long)row*ldc + col;
                C[idx] = acc[m][n][rr] + bias[col] + res[idx];
            }
        }
    }
}

// ================= 256x256 MFMA GEMM — merged-phase, 32x32x16 + XSW32 (R16, frozen) =====
// MODE: 0 bf16-out ; 2 bf16 gelu(acc+bias) ; 4 f32 acc+bias
template<int MODE>
__global__ __launch_bounds__(512, 2)
void k_gemm256(const u16* __restrict__ A, const u16* __restrict__ Bt,
               void* __restrict__ Cv, const float* __restrict__ bias,
               long lda, long ldb, long ldc, int Kk, int nTM)
{
    __shared__ alignas(128) char lds[131072];
    const int wg = xcd_swz(blockIdx.x, gridDim.x);
    const int m0 = (wg % nTM) << 8, n0 = (wg / nTM) << 8;

    const int tid = threadIdx.x, wid = tid >> 6, lane = tid & 63;
    const int l31 = lane & 31, khi = (lane >> 5) << 4;   // 32x32 frag: row/col, k-byte half
    const int wr = wid >> 2, wc = wid & 3;
    const int KT = Kk >> 6;

    const char* Asrc = (const char*)A + (long)m0 * lda * 2;
    const char* Bsrc = (const char*)Bt + (long)n0 * ldb * 2;

    auto stage = [&](int mat, int h, int kt) {
        const int d = kt & 1;
        const int kc = kt < KT ? kt : KT - 1;
        const char* src = mat ? Bsrc : Asrc;
        const long ldd = (mat ? ldb : lda) * 2;
        const long kbyte = (long)kc << 7;
        const int mo = mat << 16;
        #pragma unroll
        for (int q = 0; q < 2; ++q) {
            const int o = (h << 14) + (q << 13) + tid*16;       // linear byte in buffer
            const int row = o >> 7;
            const int offl = (o & 127) ^ XSW32(row);            // pre-swizzled source
            const char* ga = src + (long)row*ldd + kbyte + offl;
            char* ldst = lds + mo + (d << 15) + (h << 14) + (q << 13) + (wid << 10);
            __builtin_amdgcn_global_load_lds(AS1V(ga), AS3V(ldst), 16, 0, 0);
        }
    };

    bf16x8 a[2][4], b[2][4];                    // a: 2 row-blocks x 4 k-steps; b: 2 ch x 4
    f32x16 acc[4][2];                           // 4 row-blocks(32) x 2 col-blocks(32)
    #pragma unroll
    for (int i = 0; i < 4; ++i)
        #pragma unroll
        for (int j = 0; j < 2; ++j)
            #pragma unroll
            for (int e = 0; e < 16; ++e) acc[i][j][e] = 0.f;

    auto readA = [&](int d, int rh) {           // rows wr*128 + rh*64 + rb*32 + l31
        const int rowb = wr*128 + rh*64 + l31;
        #pragma unroll
        for (int rb = 0; rb < 2; ++rb) {
            const int row = rowb + (rb << 5);
            const int sw = XSW32(row);
            const int base = (d << 15) + (row << 7);
            #pragma unroll
            for (int t = 0; t < 4; ++t)
                a[rb][t] = *(const bf16x8*)(lds + base + ((khi + (t << 5)) ^ sw));
        }
    };
    auto readB = [&](int d, int ch) {           // cols wc*64 + ch*32 + l31
        const int row = wc*64 + ch*32 + l31;
        const int sw = XSW32(row);
        const int base = 65536 + (d << 15) + (row << 7);
        #pragma unroll
        for (int t = 0; t < 4; ++t)
            b[ch][t] = *(const bf16x8*)(lds + base + ((khi + (t << 5)) ^ sw));
    };
    auto mfma32 = [&](int rh, int ch) {
        __builtin_amdgcn_s_setprio(1);
        #pragma unroll
        for (int rb = 0; rb < 2; ++rb)
            #pragma unroll
            for (int t = 0; t < 4; ++t)
                acc[rh*2+rb][ch] = __builtin_amdgcn_mfma_f32_32x32x16_bf16(
                    a[rb][t], b[ch][t], acc[rh*2+rb][ch], 0, 0, 0);
        __builtin_amdgcn_s_setprio(0);
    };

    // prologue: fully stage K-tiles 0 (buf0) and 1 (buf1)
    stage(0,0,0); stage(0,1,0); stage(1,0,0); stage(1,1,0);
    stage(0,0,1); stage(0,1,1); stage(1,0,1); stage(1,1,1);
    WVM4; GBAR;

    for (int kt = 0; kt < KT; kt += 2) {
        // merged ph0+1: A-half0 + both B col-blocks of buf0; stage A(kt+1)
        readA(0,0); readB(0,0); readB(0,1); stage(0,0,kt+1); stage(0,1,kt+1);
        GBAR; mfma32(0,0); mfma32(0,1); WLG0; GBAR;
        // merged ph2+3: A-half1; stage B(kt+2); gate: tile kt+1 landed
        readA(0,1); stage(1,0,kt+2); stage(1,1,kt+2);
        GBAR; mfma32(1,1); mfma32(1,0); WLG0; WVM4; GBAR;
        // merged ph4+5: buf1 A-half0 + both B col-blocks; stage A(kt+2)
        readA(1,0); readB(1,0); readB(1,1); stage(0,0,kt+2); stage(0,1,kt+2);
        GBAR; mfma32(0,0); mfma32(0,1); WLG0; GBAR;
        // merged ph6+7: A-half1; stage B(kt+3); gate: tile kt+2 landed
        readA(1,1); stage(1,0,kt+3); stage(1,1,kt+3);
        GBAR; mfma32(1,1); mfma32(1,0); WLG0; WVM4; GBAR;
    }

    // epilogue: 32x32 C/D map: col = l31, row = (r&3) + 8*(r>>2) + 4*(lane>>5)
    const int rowAdd = ((lane >> 5) << 2);
    #pragma unroll
    for (int i = 0; i < 4; ++i) {
        #pragma unroll
        for (int r = 0; r < 16; ++r) {
            const int row = m0 + wr*128 + i*32 + (r & 3) + ((r >> 2) << 3) + rowAdd;
            const long rbase = (long)row * ldc;
            #pragma unroll
            for (int ch = 0; ch < 2; ++ch) {
                const int col = n0 + wc*64 + ch*32 + l31;
                float v = acc[i][ch][r];
                if constexpr (MODE == 0) {
                    ((u16*)Cv)[rbase + col] = f2bf(v);
                } else if constexpr (MODE == 2) {
                    float tt = v + bias[col];
                    ((u16*)Cv)[rbase + col] = f2bf(tt * 0.5f * (1.f + erff(tt * 0.70710678118f)));
                } else {
                    ((float*)Cv)[rbase + col] = v + bias[col];
                }
            }
        }
    }
}

extern "C" void kernel_launch(void* const* d_in, const int* in_sizes, int n_in,
                              void* d_out, int out_size, void* d_ws, size_t ws_size,
                              hipStream_t stream)
{
    (void)in_sizes; (void)n_in; (void)out_size; (void)ws_size;
    const int*   x   = (const int*)  d_in[0];
    const float* tok = (const float*)d_in[1];
    const float* pos = (const float*)d_in[2];
    const float* Wq  = (const float*)d_in[3];
    const float* Wk  = (const float*)d_in[4];
    const float* Wv  = (const float*)d_in[5];
    const float* Wp  = (const float*)d_in[6];
    const float* bp  = (const float*)d_in[7];
    const float* g1  = (const float*)d_in[8];
    const float* bb1 = (const float*)d_in[9];
    const float* g2  = (const float*)d_in[10];
    const float* bb2 = (const float*)d_in[11];
    const float* W1  = (const float*)d_in[12];
    const float* b1  = (const float*)d_in[13];
    const float* W2  = (const float*)d_in[14];
    const float* b2  = (const float*)d_in[15];
    const float* gF  = (const float*)d_in[16];
    const float* bF  = (const float*)d_in[17];
    const float* Wo  = (const float*)d_in[18];
    const float* bo  = (const float*)d_in[19];
    float* out = (float*)d_out;

    char* wsp = (char*)d_ws;
    auto alloc = [&](size_t bytes) { char* p = wsp; wsp += (bytes + 255) & ~(size_t)255; return p; };
    u16* WqkvT  = (u16*)alloc((size_t)L_*3*E_*E_*2);
    u16* WprojT = (u16*)alloc((size_t)L_*E_*E_*2);
    u16* W1T    = (u16*)alloc((size_t)L_*FF_*E_*2);
    u16* W2T    = (u16*)alloc((size_t)L_*E_*FF_*2);
    u16* WoutT  = (u16*)alloc((size_t)V_*E_*2);
    float* h    = (float*)alloc((size_t)M_*E_*4);
    u16* xn     = (u16*)alloc((size_t)M_*E_*2);
    u16* qkv    = (u16*)alloc((size_t)M_*3*E_*2);
    u16* vt     = (u16*)alloc((size_t)B_*H_*HD_*T_*2);
    u16* attno  = (u16*)alloc((size_t)M_*E_*2);
    u16* ffb    = (u16*)alloc((size_t)M_*FF_*2);

    dim3 tb(32, 8);
    k_packqkv<<<dim3(HD_/32, E_/32, 3*L_*H_), tb, 0, stream>>>(Wq, Wk, Wv, WqkvT);
    k_transpose<float><<<dim3(E_/32, E_/32, L_), tb, 0, stream>>>(
        Wp, WprojT, E_, E_, (long)E_, (long)E_, 1, (long)E_*E_, 0, (long)E_*E_, 0);
    k_transpose<float><<<dim3(FF_/32, E_/32, L_), tb, 0, stream>>>(
        W1, W1T, E_, FF_, (long)FF_, (long)E_, 1, (long)E_*FF_, 0, (long)FF_*E_, 0);
    k_transpose<float><<<dim3(E_/32, FF_/32, L_), tb, 0, stream>>>(
        W2, W2T, FF_, E_, (long)E_, (long)FF_, 1, (long)FF_*E_, 0, (long)E_*FF_, 0);
    k_transpose<float><<<dim3(V_/32, E_/32, 1), tb, 0, stream>>>(
        Wo, WoutT, E_, V_, (long)V_, (long)E_, 1, 0, 0, 0, 0);
    k_embed<<<dim3(M_*E_/4/256), dim3(256), 0, stream>>>(x, tok, pos, h);

    auto gemm256 = [&](int mode, const u16* A, const u16* Bt, void* C, const float* bias,
                       int Mm, int Nn, int Kk, long lda, long ldb, long ldc) {
        int nTM = Mm >> 8;
        dim3 g(nTM * (Nn >> 8)), blk(512);
        switch (mode) {
        case 0: k_gemm256<0><<<g, blk, 0, stream>>>(A, Bt, C, bias, lda, ldb, ldc, Kk, nTM); break;
        case 2: k_gemm256<2><<<g, blk, 0, stream>>>(A, Bt, C, bias, lda, ldb, ldc, Kk, nTM); break;
        case 4: k_gemm256<4><<<g, blk, 0, stream>>>(A, Bt, C, bias, lda, ldb, ldc, Kk, nTM); break;
        }
    };

    for (int l = 0; l < L_; ++l) {
        k_ln<<<dim3(M_), dim3(256), 0, stream>>>(h, g1 + (size_t)l*E_, bb1 + (size_t)l*E_, xn);
        gemm256(0, xn, WqkvT + (size_t)l*3*E_*E_, qkv, nullptr,
                M_, 3*E_, E_, (long)E_, (long)E_, (long)3*E_);
        k_transpose<u16><<<dim3(HD_/32, T_/32, B_*H_), tb, 0, stream>>>(
            qkv + 2*E_, vt, T_, HD_, (long)3*E_, (long)T_,
            H_, (long)T_*3*E_, (long)HD_, (long)H_*HD_*T_, (long)HD_*T_);
        k_flash<<<dim3(B_*H_*8), dim3(256), 0, stream>>>(qkv, vt, attno);
        k_gemmM64<<<dim3((M_/64)*(E_/128)), dim3(256), 0, stream>>>(
            attno, WprojT + (size_t)l*E_*E_, h, bp + (size_t)l*E_, h,
            (long)E_, (long)E_, (long)E_, E_, M_/64);
        k_ln<<<dim3(M_), dim3(256), 0, stream>>>(h, g2 + (size_t)l*E_, bb2 + (size_t)l*E_, xn);
        gemm256(2, xn, W1T + (size_t)l*FF_*E_, ffb, b1 + (size_t)l*FF_,
                M_, FF_, E_, (long)E_, (long)E_, (long)FF_);
        k_gemmM64<<<dim3((M_/64)*(E_/128)), dim3(256), 0, stream>>>(
            ffb, W2T + (size_t)l*E_*FF_, h, b2 + (size_t)l*E_, h,
            (long)FF_, (long)FF_, (long)E_, FF_, M_/64);
    }
    k_ln<<<dim3(M_), dim3(256), 0, stream>>>(h, gF, bF, xn);
    gemm256(4, xn, WoutT, out, bo, M_, V_, E_, (long)E_, (long)E_, (long)V_);
}

// Round 20
// 2663.559 us; speedup vs baseline: 1.0119x; 1.0081x over previous
//
#include <hip/hip_runtime.h>

#define B_ 4
#define T_ 1024
#define E_ 1024
#define H_ 16
#define HD_ 64
#define L_ 8
#define V_ 32000
#define FF_ 4096
#define M_ (B_*T_)

typedef unsigned short u16;
typedef __attribute__((ext_vector_type(8))) short bf16x8;   // 8 bf16 = 4 VGPR
typedef __attribute__((ext_vector_type(4))) float f32x4;
typedef __attribute__((ext_vector_type(16))) float f32x16;

#define AS1V(p) ((__attribute__((address_space(1))) void*)(p))
#define AS3V(p) ((__attribute__((address_space(3))) void*)(p))
#define XSW(row) (((row) & 7) << 4)
#define XSW32(row) ((((row) ^ ((row) >> 3)) & 7) << 4)

#define GBAR  asm volatile("s_barrier" ::: "memory")
#define WLG0  asm volatile("s_waitcnt lgkmcnt(0)" ::: "memory")
#define WVM4  asm volatile("s_waitcnt vmcnt(4)" ::: "memory")
#define WVM6  asm volatile("s_waitcnt vmcnt(6)" ::: "memory")
#define WVM0  asm volatile("s_waitcnt vmcnt(0)" ::: "memory")

__device__ __forceinline__ u16 f2bf(float f) {              // RNE f32->bf16
    unsigned int u = __float_as_uint(f);
    u += 0x7FFFu + ((u >> 16) & 1u);
    return (u16)(u >> 16);
}
__device__ __forceinline__ float bf2f(u16 v) {
    return __uint_as_float(((unsigned int)v) << 16);
}
__device__ __forceinline__ float ldf(const float* p, long i) { return p[i]; }
__device__ __forceinline__ float ldf(const u16*   p, long i) { return bf2f(p[i]); }

// bijective XCD swizzle (m204): nwg workgroups -> chunk per XCD
__device__ __forceinline__ int xcd_swz(int orig, int nwg) {
    int q8 = nwg >> 3, r8 = nwg & 7;
    int xcd = orig & 7, sub = orig >> 3;
    return (xcd < r8 ? xcd*(q8+1) : r8*(q8+1) + (xcd-r8)*q8) + sub;
}

// ---------------- batched tiled transpose:  dst[N][K](bf16) = src[K][N] ----------------
template<typename ST>
__global__ void k_transpose(const ST* __restrict__ src, u16* __restrict__ dst,
                            int K, int N, long srs, long drs,
                            int ZH, long szb, long szh, long dzb, long dzh)
{
    __shared__ float tile[32][33];
    int z = blockIdx.z; int zb = z / ZH, zh = z % ZH;
    const ST* s = src + (long)zb*szb + (long)zh*szh;
    u16* d = dst + (long)zb*dzb + (long)zh*dzh;
    int k0 = blockIdx.y * 32, n0 = blockIdx.x * 32;
    int tx = threadIdx.x, ty = threadIdx.y;
    for (int i = ty; i < 32; i += 8) {
        int k = k0 + i, n = n0 + tx;
        tile[i][tx] = (k < K && n < N) ? ldf(s, (long)k*srs + n) : 0.f;
    }
    __syncthreads();
    for (int i = ty; i < 32; i += 8) {
        int n = n0 + i, k = k0 + tx;
        if (n < N && k < K) d[(long)n*drs + k] = f2bf(tile[tx][i]);
    }
}

// ---------------- merged QKV weight pack: Wq/Wk/Wv [L,H,E,HD] -> WqkvT [L][3E][E] ------
__global__ void k_packqkv(const float* __restrict__ Wq, const float* __restrict__ Wk,
                          const float* __restrict__ Wv, u16* __restrict__ dst)
{
    __shared__ float tile[32][33];
    int z = blockIdx.z;                 // 0 .. 3*L*H-1
    int s = z / (L_*H_);
    int lh = z % (L_*H_);
    int l = lh / H_, hh = lh % H_;
    const float* W = (s == 0 ? Wq : (s == 1 ? Wk : Wv));
    const float* src = W + ((long)l*H_ + hh)*(long)E_*HD_;   // [E][HD]
    u16* d = dst + ((size_t)l*3*E_ + (size_t)s*E_ + (size_t)hh*HD_) * E_;
    int k0 = blockIdx.y * 32, n0 = blockIdx.x * 32;          // k over E, n over HD
    int tx = threadIdx.x, ty = threadIdx.y;
    for (int i = ty; i < 32; i += 8)
        tile[i][tx] = src[(long)(k0 + i)*HD_ + n0 + tx];
    __syncthreads();
    for (int i = ty; i < 32; i += 8)
        d[(long)(n0 + i)*E_ + k0 + tx] = f2bf(tile[tx][i]);
}

// ---------------- token+pos embedding -> h (f32) ----------------
__global__ void k_embed(const int* __restrict__ x, const float* __restrict__ tok,
                        const float* __restrict__ pos, float* __restrict__ h)
{
    long i = (long)blockIdx.x * 256 + threadIdx.x;
    int e4 = (int)(i & (E_/4 - 1));
    long bt = i >> 8;
    int t = (int)(bt & (T_ - 1));
    int id = x[bt];
    float4 a = *(const float4*)(tok + (long)id*E_ + e4*4);
    float4 p = *(const float4*)(pos + (long)t*E_ + e4*4);
    float4 o; o.x=a.x+p.x; o.y=a.y+p.y; o.z=a.z+p.z; o.w=a.w+p.w;
    *(float4*)(h + bt*E_ + e4*4) = o;
}

// ---------------- layernorm (row of E=1024, block=256) -> bf16 ----------------
__global__ void k_ln(const float* __restrict__ in, const float* __restrict__ g,
                     const float* __restrict__ b, u16* __restrict__ out)
{
    int row = blockIdx.x, tid = threadIdx.x;
    float4 v = *(const float4*)(in + (long)row*E_ + tid*4);
    float s = v.x + v.y + v.z + v.w;
    float ss = v.x*v.x + v.y*v.y + v.z*v.z + v.w*v.w;
    #pragma unroll
    for (int o = 32; o; o >>= 1) { s += __shfl_down(s, o); ss += __shfl_down(ss, o); }
    __shared__ float r0[4], r1[4];
    if ((tid & 63) == 0) { r0[tid >> 6] = s; r1[tid >> 6] = ss; }
    __syncthreads();
    s  = r0[0] + r0[1] + r0[2] + r0[3];
    ss = r1[0] + r1[1] + r1[2] + r1[3];
    float mean = s * (1.f/E_);
    float rstd = rsqrtf(ss * (1.f/E_) - mean*mean + 1e-5f);
    float4 gv = *(const float4*)(g + tid*4);
    float4 bv = *(const float4*)(b + tid*4);
    ushort4 pk;
    pk.x = f2bf((v.x - mean)*rstd*gv.x + bv.x);
    pk.y = f2bf((v.y - mean)*rstd*gv.y + bv.y);
    pk.z = f2bf((v.z - mean)*rstd*gv.z + bv.z);
    pk.w = f2bf((v.w - mean)*rstd*gv.w + bv.w);
    *(ushort4*)(out + (long)row*E_ + tid*4) = pk;
}

// ---------------- flash attention: Q-tile 128 x KV-tiles 128, online softmax ----------
__global__ __launch_bounds__(256, 2)
void k_flash(const u16* __restrict__ qkv, const u16* __restrict__ vt,
             u16* __restrict__ attno)
{
    __shared__ alignas(16) char lds[65536];
    const int wg = xcd_swz(blockIdx.x, gridDim.x);
    const int bh = wg >> 3, qt = 7 - (wg & 7);      // heavy q-tiles first
    const int b = bh >> 4, hh = bh & 15;

    const int tid = threadIdx.x, w = tid >> 6, lane = tid & 63;
    const int fr = lane & 15, sel = lane >> 4;
    const int xs = XSW(fr);

    const char* qb = (const char*)(qkv + (long)b*T_*3*E_ + (size_t)hh*HD_);
    const char* kb = (const char*)(qkv + (long)b*T_*3*E_ + E_ + (size_t)hh*HD_);
    const char* vb = (const char*)(vt + (size_t)bh*HD_*T_);
    const int q0 = qt << 7;

    bf16x8 qa[2][2];
    #pragma unroll
    for (int rf = 0; rf < 2; ++rf)
        #pragma unroll
        for (int t = 0; t < 2; ++t) {
            int row = q0 + w*32 + rf*16 + fr;
            qa[rf][t] = *(const bf16x8*)(qb + (long)row*(3*E_*2) + t*64 + sel*16);
        }

    f32x4 oacc[2][4];
    float mrow[2][4], lrow[2][4];
    #pragma unroll
    for (int rf = 0; rf < 2; ++rf) {
        #pragma unroll
        for (int cf = 0; cf < 4; ++cf) oacc[rf][cf] = (f32x4){0.f,0.f,0.f,0.f};
        #pragma unroll
        for (int r = 0; r < 4; ++r) { mrow[rf][r] = -1e30f; lrow[rf][r] = 0.f; }
    }

    char* Ks  = lds;
    char* Vts = lds + 16384;
    char* Pw  = lds + 32768 + w*8192;

    for (int kv = 0; kv <= qt; ++kv) {
        const int s0 = kv << 7;
        __syncthreads();
        #pragma unroll
        for (int c = 0; c < 4; ++c) {              // K tile -> Ks (pre-swizzled source)
            int o = c*4096 + tid*16;
            int row = o >> 7;
            int offl = (o & 127) ^ XSW(row);
            const char* ga = kb + (long)(s0 + row)*(3*E_*2) + offl;
            __builtin_amdgcn_global_load_lds(AS1V(ga), AS3V(Ks + c*4096 + (tid >> 6)*1024), 16, 0, 0);
        }
        #pragma unroll
        for (int c = 0; c < 4; ++c) {              // V^T tile -> Vts
            int o = c*4096 + tid*16;
            int row = o >> 8;
            int offl = (o & 255) ^ XSW(row);
            const char* ga = vb + (long)row*(T_*2) + s0*2 + offl;
            __builtin_amdgcn_global_load_lds(AS1V(ga), AS3V(Vts + c*4096 + (tid >> 6)*1024), 16, 0, 0);
        }
        __syncthreads();

        // ---- QK^T ----
        f32x4 sacc[2][8];
        #pragma unroll
        for (int rf = 0; rf < 2; ++rf)
            #pragma unroll
            for (int cf = 0; cf < 8; ++cf) sacc[rf][cf] = (f32x4){0.f,0.f,0.f,0.f};
        __builtin_amdgcn_s_setprio(1);
        #pragma unroll
        for (int t = 0; t < 2; ++t) {
            bf16x8 kf[8];
            #pragma unroll
            for (int cf = 0; cf < 8; ++cf) {
                int srow = cf*16 + fr;
                kf[cf] = *(const bf16x8*)(Ks + srow*128 + ((t*64 + sel*16) ^ xs));
            }
            #pragma unroll
            for (int rf = 0; rf < 2; ++rf)
                #pragma unroll
                for (int cf = 0; cf < 8; ++cf)
                    sacc[rf][cf] = __builtin_amdgcn_mfma_f32_16x16x32_bf16(
                        qa[rf][t], kf[cf], sacc[rf][cf], 0, 0, 0);
        }
        __builtin_amdgcn_s_setprio(0);

        // ---- scale + causal mask + online softmax ----
        const bool diag = (kv == qt);
        #pragma unroll
        for (int rf = 0; rf < 2; ++rf)
            #pragma unroll
            for (int r = 0; r < 4; ++r) {
                int rowg = q0 + w*32 + rf*16 + sel*4 + r;
                float mx = -1e30f;
                #pragma unroll
                for (int cf = 0; cf < 8; ++cf) {
                    float v = sacc[rf][cf][r] * 0.03125f;
                    if (diag && (s0 + cf*16 + fr) > rowg) v = -1e30f;
                    sacc[rf][cf][r] = v;
                    mx = fmaxf(mx, v);
                }
                #pragma unroll
                for (int o = 1; o < 16; o <<= 1) mx = fmaxf(mx, __shfl_xor(mx, o));
                float mold = mrow[rf][r];
                float mnew = fmaxf(mold, mx);
                float alpha = __expf(mold - mnew);
                float sum = 0.f;
                #pragma unroll
                for (int cf = 0; cf < 8; ++cf) {
                    float p = __expf(sacc[rf][cf][r] - mnew);
                    sacc[rf][cf][r] = p;
                    sum += p;
                }
                #pragma unroll
                for (int o = 1; o < 16; o <<= 1) sum += __shfl_xor(sum, o);
                mrow[rf][r] = mnew;
                lrow[rf][r] = lrow[rf][r]*alpha + sum;
                #pragma unroll
                for (int cf = 0; cf < 4; ++cf) oacc[rf][cf][r] *= alpha;
            }

        // ---- P -> wave-private LDS (bf16, swizzled) ----
        #pragma unroll
        for (int rf = 0; rf < 2; ++rf)
            #pragma unroll
            for (int r = 0; r < 4; ++r) {
                int rl = rf*16 + sel*4 + r;
                char* base = Pw + rl*256;
                int sw = XSW(rl);
                #pragma unroll
                for (int cf = 0; cf < 8; ++cf)
                    *(u16*)(base + ((cf*32 + fr*2) ^ sw)) = f2bf(sacc[rf][cf][r]);
            }

        // ---- PV: O += P @ V ----
        __builtin_amdgcn_s_setprio(1);
        #pragma unroll
        for (int ts = 0; ts < 4; ++ts) {
            bf16x8 pa[2], vf[4];
            #pragma unroll
            for (int rf = 0; rf < 2; ++rf)
                pa[rf] = *(const bf16x8*)(Pw + (rf*16 + fr)*256 + ((ts*64 + sel*16) ^ xs));
            #pragma unroll
            for (int cf = 0; cf < 4; ++cf)
                vf[cf] = *(const bf16x8*)(Vts + (cf*16 + fr)*256 + ((ts*64 + sel*16) ^ xs));
            #pragma unroll
            for (int rf = 0; rf < 2; ++rf)
                #pragma unroll
                for (int cf = 0; cf < 4; ++cf)
                    oacc[rf][cf] = __builtin_amdgcn_mfma_f32_16x16x32_bf16(
                        pa[rf], vf[cf], oacc[rf][cf], 0, 0, 0);
        }
        __builtin_amdgcn_s_setprio(0);
    }

    u16* ab = attno + ((long)b*T_ + q0 + w*32)*E_ + (size_t)hh*HD_;
    #pragma unroll
    for (int rf = 0; rf < 2; ++rf)
        #pragma unroll
        for (int r = 0; r < 4; ++r) {
            float rinv = 1.f / lrow[rf][r];
            int rl = rf*16 + sel*4 + r;
            #pragma unroll
            for (int cf = 0; cf < 4; ++cf)
                ab[(long)rl*E_ + cf*16 + fr] = f2bf(oacc[rf][cf][r] * rinv);
        }
}

// ---------------- 64x128 BK=64 dbuf swizzled GEMM: f32 = acc + bias + res ----------------
// BM=64 -> grid 512 blocks -> 2 blocks/CU, re-read counts unchanged vs 128x128.
__global__ __launch_bounds__(256, 2)
void k_gemmM64(const u16* __restrict__ A, const u16* __restrict__ Bt,
               float* __restrict__ C, const float* __restrict__ bias,
               const float* __restrict__ res,
               long lda, long ldb, long ldc, int Kk, int nTM)
{
    __shared__ alignas(128) char lds[49152];
    const int wg = xcd_swz(blockIdx.x, gridDim.x);
    const int m0 = (wg % nTM) << 6, n0 = (wg / nTM) << 7;

    const int tid = threadIdx.x, wid = tid >> 6, lane = tid & 63;
    const int fr = lane & 15, sel = lane >> 4;
    const int wr = wid >> 1, wc = wid & 1;
    const int xs = XSW(fr);
    const int KT = Kk >> 6;

    const long lda2 = lda*2, ldb2 = ldb*2;
    const int rowL = tid >> 3;                         // 0..31
    const int offl = (((tid & 7) ^ (rowL & 7)) << 4);  // pre-swizzled src offset
    const char* pA = (const char*)A + ((long)(m0 + rowL))*lda2 + offl;
    const char* pB = (const char*)Bt + ((long)(n0 + rowL))*ldb2 + offl;
    char* ldwA = lds + (wid << 10);
    char* ldwB = lds + 16384 + (wid << 10);

    auto stageA = [&](int kt) {                        // 2 loads: rows 0..63
        const int d = (kt & 1) << 13;
        const long kb = (long)kt << 7;
        #pragma unroll
        for (int c = 0; c < 2; ++c)
            __builtin_amdgcn_global_load_lds(AS1V(pA + (long)(c << 5)*lda2 + kb),
                                             AS3V(ldwA + d + (c << 12)), 16, 0, 0);
    };
    auto stageB = [&](int kt) {                        // 4 loads: rows 0..127
        const int d = (kt & 1) << 14;
        const long kb = (long)kt << 7;
        #pragma unroll
        for (int c = 0; c < 4; ++c)
            __builtin_amdgcn_global_load_lds(AS1V(pB + (long)(c << 5)*ldb2 + kb),
                                             AS3V(ldwB + d + (c << 12)), 16, 0, 0);
    };

    f32x4 acc[2][4];
    #pragma unroll
    for (int i = 0; i < 2; ++i)
        #pragma unroll
        for (int j = 0; j < 4; ++j) acc[i][j] = (f32x4){0.f,0.f,0.f,0.f};

    stageA(0); stageB(0); stageA(1); stageB(1);
    WVM6; GBAR;

    for (int t = 0; t < KT; ++t) {
        const int dA = (t & 1) << 13, dB = (t & 1) << 14;
        bf16x8 a[2][2], b[4][2];
        #pragma unroll
        for (int m = 0; m < 2; ++m)
            #pragma unroll
            for (int tt = 0; tt < 2; ++tt)
                a[m][tt] = *(const bf16x8*)(lds + dA +
                    (((wr*32 + m*16 + fr) << 7) + ((sel*16 + tt*64) ^ xs)));
        #pragma unroll
        for (int n = 0; n < 4; ++n)
            #pragma unroll
            for (int tt = 0; tt < 2; ++tt)
                b[n][tt] = *(const bf16x8*)(lds + 16384 + dB +
                    (((wc*64 + n*16 + fr) << 7) + ((sel*16 + tt*64) ^ xs)));
        __builtin_amdgcn_s_setprio(1);
        #pragma unroll
        for (int m = 0; m < 2; ++m)
            #pragma unroll
            for (int n = 0; n < 4; ++n)
                #pragma unroll
                for (int tt = 0; tt < 2; ++tt)
                    acc[m][n] = __builtin_amdgcn_mfma_f32_16x16x32_bf16(
                        a[m][tt], b[n][tt], acc[m][n], 0, 0, 0);
        __builtin_amdgcn_s_setprio(0);
        GBAR;                               // all waves' reads of buf d complete
        if (t + 2 < KT) {
            stageA(t+2); stageB(t+2);       // overwrite buf d (t+2 has same parity)
            WVM6;                           // wait stage(t+1): 6 newer in flight
        } else {
            WVM0;                           // tail: drain everything
        }
        GBAR;
    }

    #pragma unroll
    for (int m = 0; m < 2; ++m) {
        #pragma unroll
        for (int rr = 0; rr < 4; ++rr) {
            const int row = m0 + wr*32 + m*16 + sel*4 + rr;
            #pragma unroll
            for (int n = 0; n < 4; ++n) {
                const int col = n0 + wc*64 + n*16 + fr;
                long idx = (long)row*ldc + col;
                C[idx] = acc[m][n][rr] + bias[col] + res[idx];
            }
        }
    }
}

// ================= 256x256 MFMA GEMM — merged-phase, 32x32x16 + XSW32 (R16 base) =====
// MODE: 0 bf16-out ; 2 bf16 gelu(acc+bias) ; 4 f32 acc+bias (NT stores: full 128B
// lines per 32-lane group in the 32x32 layout, so no partial-line amplification;
// protects L2/L3-resident A/B panels from the 524 MB logits write stream).
template<int MODE>
__global__ __launch_bounds__(512, 2)
void k_gemm256(const u16* __restrict__ A, const u16* __restrict__ Bt,
               void* __restrict__ Cv, const float* __restrict__ bias,
               long lda, long ldb, long ldc, int Kk, int nTM)
{
    __shared__ alignas(128) char lds[131072];
    const int wg = xcd_swz(blockIdx.x, gridDim.x);
    const int m0 = (wg % nTM) << 8, n0 = (wg / nTM) << 8;

    const int tid = threadIdx.x, wid = tid >> 6, lane = tid & 63;
    const int l31 = lane & 31, khi = (lane >> 5) << 4;   // 32x32 frag: row/col, k-byte half
    const int wr = wid >> 2, wc = wid & 3;
    const int KT = Kk >> 6;

    const char* Asrc = (const char*)A + (long)m0 * lda * 2;
    const char* Bsrc = (const char*)Bt + (long)n0 * ldb * 2;

    auto stage = [&](int mat, int h, int kt) {
        const int d = kt & 1;
        const int kc = kt < KT ? kt : KT - 1;
        const char* src = mat ? Bsrc : Asrc;
        const long ldd = (mat ? ldb : lda) * 2;
        const long kbyte = (long)kc << 7;
        const int mo = mat << 16;
        #pragma unroll
        for (int q = 0; q < 2; ++q) {
            const int o = (h << 14) + (q << 13) + tid*16;       // linear byte in buffer
            const int row = o >> 7;
            const int offl = (o & 127) ^ XSW32(row);            // pre-swizzled source
            const char* ga = src + (long)row*ldd + kbyte + offl;
            char* ldst = lds + mo + (d << 15) + (h << 14) + (q << 13) + (wid << 10);
            __builtin_amdgcn_global_load_lds(AS1V(ga), AS3V(ldst), 16, 0, 0);
        }
    };

    bf16x8 a[2][4], b[2][4];                    // a: 2 row-blocks x 4 k-steps; b: 2 ch x 4
    f32x16 acc[4][2];                           // 4 row-blocks(32) x 2 col-blocks(32)
    #pragma unroll
    for (int i = 0; i < 4; ++i)
        #pragma unroll
        for (int j = 0; j < 2; ++j)
            #pragma unroll
            for (int e = 0; e < 16; ++e) acc[i][j][e] = 0.f;

    auto readA = [&](int d, int rh) {           // rows wr*128 + rh*64 + rb*32 + l31
        const int rowb = wr*128 + rh*64 + l31;
        #pragma unroll
        for (int rb = 0; rb < 2; ++rb) {
            const int row = rowb + (rb << 5);
            const int sw = XSW32(row);
            const int base = (d << 15) + (row << 7);
            #pragma unroll
            for (int t = 0; t < 4; ++t)
                a[rb][t] = *(const bf16x8*)(lds + base + ((khi + (t << 5)) ^ sw));
        }
    };
    auto readB = [&](int d, int ch) {           // cols wc*64 + ch*32 + l31
        const int row = wc*64 + ch*32 + l31;
        const int sw = XSW32(row);
        const int base = 65536 + (d << 15) + (row << 7);
        #pragma unroll
        for (int t = 0; t < 4; ++t)
            b[ch][t] = *(const bf16x8*)(lds + base + ((khi + (t << 5)) ^ sw));
    };
    auto mfma32 = [&](int rh, int ch) {
        __builtin_amdgcn_s_setprio(1);
        #pragma unroll
        for (int rb = 0; rb < 2; ++rb)
            #pragma unroll
            for (int t = 0; t < 4; ++t)
                acc[rh*2+rb][ch] = __builtin_amdgcn_mfma_f32_32x32x16_bf16(
                    a[rb][t], b[ch][t], acc[rh*2+rb][ch], 0, 0, 0);
        __builtin_amdgcn_s_setprio(0);
    };

    // prologue: fully stage K-tiles 0 (buf0) and 1 (buf1)
    stage(0,0,0); stage(0,1,0); stage(1,0,0); stage(1,1,0);
    stage(0,0,1); stage(0,1,1); stage(1,0,1); stage(1,1,1);
    WVM4; GBAR;

    for (int kt = 0; kt < KT; kt += 2) {
        // merged ph0+1: A-half0 + both B col-blocks of buf0; stage A(kt+1)
        readA(0,0); readB(0,0); readB(0,1); stage(0,0,kt+1); stage(0,1,kt+1);
        GBAR; mfma32(0,0); mfma32(0,1); WLG0; GBAR;
        // merged ph2+3: A-half1; stage B(kt+2); gate: tile kt+1 landed
        readA(0,1); stage(1,0,kt+2); stage(1,1,kt+2);
        GBAR; mfma32(1,1); mfma32(1,0); WLG0; WVM4; GBAR;
        // merged ph4+5: buf1 A-half0 + both B col-blocks; stage A(kt+2)
        readA(1,0); readB(1,0); readB(1,1); stage(0,0,kt+2); stage(0,1,kt+2);
        GBAR; mfma32(0,0); mfma32(0,1); WLG0; GBAR;
        // merged ph6+7: A-half1; stage B(kt+3); gate: tile kt+2 landed
        readA(1,1); stage(1,0,kt+3); stage(1,1,kt+3);
        GBAR; mfma32(1,1); mfma32(1,0); WLG0; WVM4; GBAR;
    }

    // epilogue: 32x32 C/D map: col = l31, row = (r&3) + 8*(r>>2) + 4*(lane>>5)
    const int rowAdd = ((lane >> 5) << 2);
    #pragma unroll
    for (int i = 0; i < 4; ++i) {
        #pragma unroll
        for (int r = 0; r < 16; ++r) {
            const int row = m0 + wr*128 + i*32 + (r & 3) + ((r >> 2) << 3) + rowAdd;
            const long rbase = (long)row * ldc;
            #pragma unroll
            for (int ch = 0; ch < 2; ++ch) {
                const int col = n0 + wc*64 + ch*32 + l31;
                float v = acc[i][ch][r];
                if constexpr (MODE == 0) {
                    ((u16*)Cv)[rbase + col] = f2bf(v);
                } else if constexpr (MODE == 2) {
                    float tt = v + bias[col];
                    ((u16*)Cv)[rbase + col] = f2bf(tt * 0.5f * (1.f + erff(tt * 0.70710678118f)));
                } else {
                    __builtin_nontemporal_store(v + bias[col], &((float*)Cv)[rbase + col]);
                }
            }
        }
    }
}

extern "C" void kernel_launch(void* const* d_in, const int* in_sizes, int n_in,
                              void* d_out, int out_size, void* d_ws, size_t ws_size,
                              hipStream_t stream)
{
    (void)in_sizes; (void)n_in; (void)out_size; (void)ws_size;
    const int*   x   = (const int*)  d_in[0];
    const float* tok = (const float*)d_in[1];
    const float* pos = (const float*)d_in[2];
    const float* Wq  = (const float*)d_in[3];
    const float* Wk  = (const float*)d_in[4];
    const float* Wv  = (const float*)d_in[5];
    const float* Wp  = (const float*)d_in[6];
    const float* bp  = (const float*)d_in[7];
    const float* g1  = (const float*)d_in[8];
    const float* bb1 = (const float*)d_in[9];
    const float* g2  = (const float*)d_in[10];
    const float* bb2 = (const float*)d_in[11];
    const float* W1  = (const float*)d_in[12];
    const float* b1  = (const float*)d_in[13];
    const float* W2  = (const float*)d_in[14];
    const float* b2  = (const float*)d_in[15];
    const float* gF  = (const float*)d_in[16];
    const float* bF  = (const float*)d_in[17];
    const float* Wo  = (const float*)d_in[18];
    const float* bo  = (const float*)d_in[19];
    float* out = (float*)d_out;

    char* wsp = (char*)d_ws;
    auto alloc = [&](size_t bytes) { char* p = wsp; wsp += (bytes + 255) & ~(size_t)255; return p; };
    u16* WqkvT  = (u16*)alloc((size_t)L_*3*E_*E_*2);
    u16* WprojT = (u16*)alloc((size_t)L_*E_*E_*2);
    u16* W1T    = (u16*)alloc((size_t)L_*FF_*E_*2);
    u16* W2T    = (u16*)alloc((size_t)L_*E_*FF_*2);
    u16* WoutT  = (u16*)alloc((size_t)V_*E_*2);
    float* h    = (float*)alloc((size_t)M_*E_*4);
    u16* xn     = (u16*)alloc((size_t)M_*E_*2);
    u16* qkv    = (u16*)alloc((size_t)M_*3*E_*2);
    u16* vt     = (u16*)alloc((size_t)B_*H_*HD_*T_*2);
    u16* attno  = (u16*)alloc((size_t)M_*E_*2);
    u16* ffb    = (u16*)alloc((size_t)M_*FF_*2);

    dim3 tb(32, 8);
    k_packqkv<<<dim3(HD_/32, E_/32, 3*L_*H_), tb, 0, stream>>>(Wq, Wk, Wv, WqkvT);
    k_transpose<float><<<dim3(E_/32, E_/32, L_), tb, 0, stream>>>(
        Wp, WprojT, E_, E_, (long)E_, (long)E_, 1, (long)E_*E_, 0, (long)E_*E_, 0);
    k_transpose<float><<<dim3(FF_/32, E_/32, L_), tb, 0, stream>>>(
        W1, W1T, E_, FF_, (long)FF_, (long)E_, 1, (long)E_*FF_, 0, (long)FF_*E_, 0);
    k_transpose<float><<<dim3(E_/32, FF_/32, L_), tb, 0, stream>>>(
        W2, W2T, FF_, E_, (long)E_, (long)FF_, 1, (long)FF_*E_, 0, (long)E_*FF_, 0);
    k_transpose<float><<<dim3(V_/32, E_/32, 1), tb, 0, stream>>>(
        Wo, WoutT, E_, V_, (long)V_, (long)E_, 1, 0, 0, 0, 0);
    k_embed<<<dim3(M_*E_/4/256), dim3(256), 0, stream>>>(x, tok, pos, h);

    auto gemm256 = [&](int mode, const u16* A, const u16* Bt, void* C, const float* bias,
                       int Mm, int Nn, int Kk, long lda, long ldb, long ldc) {
        int nTM = Mm >> 8;
        dim3 g(nTM * (Nn >> 8)), blk(512);
        switch (mode) {
        case 0: k_gemm256<0><<<g, blk, 0, stream>>>(A, Bt, C, bias, lda, ldb, ldc, Kk, nTM); break;
        case 2: k_gemm256<2><<<g, blk, 0, stream>>>(A, Bt, C, bias, lda, ldb, ldc, Kk, nTM); break;
        case 4: k_gemm256<4><<<g, blk, 0, stream>>>(A, Bt, C, bias, lda, ldb, ldc, Kk, nTM); break;
        }
    };

    for (int l = 0; l < L_; ++l) {
        k_ln<<<dim3(M_), dim3(256), 0, stream>>>(h, g1 + (size_t)l*E_, bb1 + (size_t)l*E_, xn);
        gemm256(0, xn, WqkvT + (size_t)l*3*E_*E_, qkv, nullptr,
                M_, 3*E_, E_, (long)E_, (long)E_, (long)3*E_);
        k_transpose<u16><<<dim3(HD_/32, T_/32, B_*H_), tb, 0, stream>>>(
            qkv + 2*E_, vt, T_, HD_, (long)3*E_, (long)T_,
            H_, (long)T_*3*E_, (long)HD_, (long)H_*HD_*T_, (long)HD_*T_);
        k_flash<<<dim3(B_*H_*8), dim3(256), 0, stream>>>(qkv, vt, attno);
        k_gemmM64<<<dim3((M_/64)*(E_/128)), dim3(256), 0, stream>>>(
            attno, WprojT + (size_t)l*E_*E_, h, bp + (size_t)l*E_, h,
            (long)E_, (long)E_, (long)E_, E_, M_/64);
        k_ln<<<dim3(M_), dim3(256), 0, stream>>>(h, g2 + (size_t)l*E_, bb2 + (size_t)l*E_, xn);
        gemm256(2, xn, W1T + (size_t)l*FF_*E_, ffb, b1 + (size_t)l*FF_,
                M_, FF_, E_, (long)E_, (long)E_, (long)FF_);
        k_gemmM64<<<dim3((M_/64)*(E_/128)), dim3(256), 0, stream>>>(
            ffb, W2T + (size_t)l*E_*FF_, h, b2 + (size_t)l*E_, h,
            (long)FF_, (long)FF_, (long)E_, FF_, M_/64);
    }
    k_ln<<<dim3(M_), dim3(256), 0, stream>>>(h, gF, bF, xn);
    gemm256(4, xn, WoutT, out, bo, M_, V_, E_, (long)E_, (long)E_, (long)V_);
}